// Round 2
// baseline (1353.289 us; speedup 1.0000x reference)
//
#include <hip/hip_runtime.h>
#include <math.h>

// Problem constants (fixed by the reference).
#define DD 2001      // feature dim
#define CC 20        // classes
#define NN 100000    // rows
#define REGC 0.001f

#define CH 64        // floats per row per chunk
#define NFULL 31     // 31*64 = 1984 full-chunk floats
#define DTAIL 1984   // tail: d = 1984..2000 (17 floats), read per-lane
#define RSTR 68      // LDS row stride (floats): 272 B, 16B-aligned, bank-groups tile

__device__ __forceinline__ float4 ld4(const float* p) {
  return *reinterpret_cast<const float4*>(p);
}

// One wave (64 threads) per block; lane i computes row blockIdx.x*64 + i.
// X is staged through LDS so global reads are coalesced (4 rows x 256 B
// contiguous per staging instruction); weights stay wave-uniform -> s_load.
__global__ __launch_bounds__(64) void loss_main(
    const float* __restrict__ X,
    const float* __restrict__ Wt,   // [D][C] transposed weights
    const int* __restrict__ Y,
    float* __restrict__ out) {
  __shared__ float xs[64 * RSTR];   // 17408 B
  const int lane = threadIdx.x;
  const int rowbase = blockIdx.x * 64;

  const int myrow0 = rowbase + lane;
  const bool valid = myrow0 < NN;
  const int myrow = valid ? myrow0 : NN - 1;

  // Staging map: instr q (0..15): lane l -> row rowbase + q*4 + (l>>4),
  // float4 index (l&15). 16 lanes x 16 B = 256 B contiguous per row segment.
  const int srow = lane >> 4;   // 0..3
  const int sf   = lane & 15;   // 0..15

  float acc[CC];
#pragma unroll
  for (int c = 0; c < CC; ++c) acc[c] = 0.f;

  float4 va[16], vb[16];

  // Precompute clamped staging row bases (rows >= NN re-read row NN-1).
  size_t sbase[16];
#pragma unroll
  for (int q = 0; q < 16; ++q) {
    int r = rowbase + q * 4 + srow;
    r = r < NN ? r : NN - 1;
    sbase[q] = (size_t)r * DD + sf * 4;
  }

  // Prologue: load chunk 0 into va.
#pragma unroll
  for (int q = 0; q < 16; ++q) va[q] = ld4(X + sbase[q]);

  // Body: write cur chunk k to LDS, prefetch chunk k+1 into nxt, compute k.
  auto body = [&](float4 (&cur)[16], float4 (&nxt)[16], int k) {
    // stage chunk k into LDS (b128 writes, bank-groups tile)
#pragma unroll
    for (int q = 0; q < 16; ++q)
      *reinterpret_cast<float4*>(&xs[(q * 4 + srow) * RSTR + sf * 4]) = cur[q];
    // prefetch chunk k+1 (issued ~2500 cycles before its use)
    if (k + 1 < NFULL) {
#pragma unroll
      for (int q = 0; q < 16; ++q)
        nxt[q] = ld4(X + sbase[q] + (size_t)(k + 1) * CH);
    }
    // compute chunk k: lane reads its own row from LDS as float4s
    const int dbase = k * CH;
#pragma unroll
    for (int f = 0; f < 16; ++f) {
      float4 x4 = *reinterpret_cast<const float4*>(&xs[lane * RSTR + f * 4]);
      const float xv[4] = {x4.x, x4.y, x4.z, x4.w};
#pragma unroll
      for (int j = 0; j < 4; ++j) {
        const int d = dbase + f * 4 + j;   // uniform -> scalar W loads
        const float xx = xv[j];
#pragma unroll
        for (int c = 0; c < CC; ++c)
          acc[c] = fmaf(xx, Wt[d * CC + c], acc[c]);
      }
    }
  };

  // 31 chunks: 15 ping-pong pairs + final chunk (in va).
  for (int k = 0; k < NFULL - 1; k += 2) {
    body(va, vb, k);
    body(vb, va, k + 1);
  }
  body(va, vb, NFULL - 1);

  // Tail d = 1984..2000: per-lane direct reads (0.85% of traffic).
  {
    const float* xr = X + (size_t)myrow * DD;
#pragma unroll
    for (int d = DTAIL; d < DD; ++d) {
      const float xx = xr[d];
#pragma unroll
      for (int c = 0; c < CC; ++c)
        acc[c] = fmaf(xx, Wt[d * CC + c], acc[c]);
    }
  }

  // per-row loss: picked + logsumexp(-scores)
  float mx = -3.402823466e38f;
#pragma unroll
  for (int c = 0; c < CC; ++c) mx = fmaxf(mx, -acc[c]);
  float s = 0.f;
#pragma unroll
  for (int c = 0; c < CC; ++c) s += __expf(-acc[c] - mx);
  const int y = valid ? Y[myrow] : 0;
  float picked = 0.f;
#pragma unroll
  for (int c = 0; c < CC; ++c) picked = (c == y) ? acc[c] : picked;
  float li = picked + mx + __logf(s);
  li = valid ? li : 0.f;

  // wave (==block) butterfly reduction over 64 lanes
#pragma unroll
  for (int off = 32; off > 0; off >>= 1) li += __shfl_xor(li, off, 64);
  if (lane == 0) atomicAdd(out, li * (1.0f / NN));
}

// Runs FIRST on the stream: out[0] = REG * ||init_weights||_F (plain store).
__global__ void reg_kernel(const float* __restrict__ IW, float* __restrict__ out) {
  __shared__ float red[256];
  float s = 0.f;
  for (int i = threadIdx.x; i < CC * DD; i += 256) {
    float v = IW[i];
    s += v * v;
  }
  red[threadIdx.x] = s;
  __syncthreads();
  for (int w = 128; w > 0; w >>= 1) {
    if (threadIdx.x < w) red[threadIdx.x] += red[threadIdx.x + w];
    __syncthreads();
  }
  if (threadIdx.x == 0) out[0] = REGC * sqrtf(red[0]);
}

__global__ void transpose_w(const float* __restrict__ W, float* __restrict__ Wt) {
  int i = blockIdx.x * 256 + threadIdx.x;
  if (i < CC * DD) {
    int c = i / DD;
    int d = i - c * DD;
    Wt[d * CC + c] = W[i];
  }
}

extern "C" void kernel_launch(void* const* d_in, const int* in_sizes, int n_in,
                              void* d_out, int out_size, void* d_ws, size_t ws_size,
                              hipStream_t stream) {
  const float* W  = (const float*)d_in[0];   // weights [C, D]
  const float* X  = (const float*)d_in[1];   // X [N, D]
  const int*   Y  = (const int*)d_in[2];     // Y [N]
  const float* IW = (const float*)d_in[3];   // init_weights [C, D]
  float* out = (float*)d_out;

  // 1) constant reg term (overwrites poisoned d_out)
  reg_kernel<<<1, 256, 0, stream>>>(IW, out);

  // 2) transpose weights -> Wt[d][c] in workspace (contiguous scalar loads)
  float* Wt = (float*)d_ws;  // ws_size is GBs; 160 KB needed
  transpose_w<<<(CC * DD + 255) / 256, 256, 0, stream>>>(W, Wt);

  // 3) main streaming kernel: one 64-thread wave per 64 rows
  const int nblocks = (NN + 63) / 64;  // 1563
  loss_main<<<nblocks, 64, 0, stream>>>(X, Wt, Y, out);
}

// Round 3
// 1145.921 us; speedup vs baseline: 1.1810x; 1.1810x over previous
//
#include <hip/hip_runtime.h>
#include <math.h>

// Problem constants (fixed by the reference).
#define DD 2001      // feature dim
#define CC 20        // classes
#define NN 100000    // rows
#define REGC 0.001f

#define NSLICE 4     // D-dimension split across waves
#define NRG 1563     // ceil(NN / 64) row groups, 64 rows (one per lane) per wave

// Workspace layout: part[NSLICE][CC][NN] floats (32 MB, fully overwritten ->
// no zero-init needed), then Wt[DD][CC] at byte offset PART_BYTES.
#define PART_BYTES ((size_t)NSLICE * CC * NN * 4)

__device__ __forceinline__ float4 ld4(const float* p) {
  return *reinterpret_cast<const float4*>(p);
}

// One wave (64 threads) per block. Lane l owns row blockIdx.x*64 + l.
// blockIdx.y = D-slice. X staged through LDS (coalesced 64B-per-row global
// loads), W chunk staged through LDS and consumed via broadcast ds_read_b128
// (all lanes same address -> conflict-free, no scalar-load stalls).
__global__ __launch_bounds__(64, 4) void loss_partial(
    const float* __restrict__ X,
    const float* __restrict__ Wt,    // [DD][CC] transposed weights
    float* __restrict__ part) {      // [NSLICE][CC][NN]
  __shared__ float xs[64 * 20];      // 16 floats/row + 4 pad (banks) = 5120 B
  __shared__ float wc[16 * 20];      // W chunk [d=16][c=20] = 1280 B
  const int lane = threadIdx.x;
  const int rg = blockIdx.x;
  const int slice = blockIdx.y;
  const int rowbase = rg * 64;
  const int row0 = rowbase + lane;
  const bool valid = row0 < NN;

  // Chunk ranges over 125 full 16-float chunks: {32,31,31,31}; slice 3 adds d=2000 tail.
  const int ch0 = (slice == 0) ? 0 : (32 + 31 * (slice - 1));
  const int nch = (slice == 0) ? 32 : 31;

  // X staging map: instr q (0..3): lane l -> row rowbase + q*16 + (l>>2),
  // float4 (l&3). Per instr: 16 rows x 64 B contiguous segments.
  const int srow = lane >> 2;
  const int sf = lane & 3;
  unsigned sb[4];
#pragma unroll
  for (int q = 0; q < 4; ++q) {
    int r = rowbase + q * 16 + srow;
    r = r < NN ? r : NN - 1;           // clamp OOB rows (results discarded)
    sb[q] = (unsigned)r * DD + sf * 4u;
  }

  float acc[CC];
#pragma unroll
  for (int c = 0; c < CC; ++c) acc[c] = 0.f;

  // Prefetch chunk ch0 into registers.
  float4 xa[4];
  float4 wa0, wa1;
  {
    const unsigned doff = (unsigned)ch0 * 16u;
#pragma unroll
    for (int q = 0; q < 4; ++q) xa[q] = ld4(X + sb[q] + doff);
    const float* wp = Wt + (size_t)ch0 * (16 * CC);   // 320 floats per chunk
    wa0 = ld4(wp + lane * 4);                          // floats 0..255
    wa1 = (lane < 16) ? ld4(wp + 256 + lane * 4)       // floats 256..319
                      : float4{0, 0, 0, 0};
  }

#pragma unroll 1
  for (int ch = 0; ch < nch; ++ch) {
    // Stage current chunk regs -> LDS (in-order DS pipe within the wave).
#pragma unroll
    for (int q = 0; q < 4; ++q)
      *reinterpret_cast<float4*>(&xs[(q * 16 + srow) * 20 + sf * 4]) = xa[q];
    *reinterpret_cast<float4*>(&wc[lane * 4]) = wa0;
    if (lane < 16) *reinterpret_cast<float4*>(&wc[256 + lane * 4]) = wa1;

    // Prefetch next chunk during compute.
    if (ch + 1 < nch) {
      const unsigned doff = (unsigned)(ch0 + ch + 1) * 16u;
#pragma unroll
      for (int q = 0; q < 4; ++q) xa[q] = ld4(X + sb[q] + doff);
      const float* wp = Wt + (size_t)(ch0 + ch + 1) * (16 * CC);
      wa0 = ld4(wp + lane * 4);
      if (lane < 16) wa1 = ld4(wp + 256 + lane * 4);
    }

    // Compute: 16 d-values x 20 classes. W via broadcast b128 LDS reads.
#pragma unroll
    for (int f = 0; f < 4; ++f) {
      const float4 xv = *reinterpret_cast<const float4*>(&xs[lane * 20 + f * 4]);
      const float xj[4] = {xv.x, xv.y, xv.z, xv.w};
#pragma unroll
      for (int j = 0; j < 4; ++j) {
        const int d = f * 4 + j;
        const float xx = xj[j];
        const float4 w0 = *reinterpret_cast<const float4*>(&wc[d * 20 + 0]);
        const float4 w1 = *reinterpret_cast<const float4*>(&wc[d * 20 + 4]);
        const float4 w2 = *reinterpret_cast<const float4*>(&wc[d * 20 + 8]);
        const float4 w3 = *reinterpret_cast<const float4*>(&wc[d * 20 + 12]);
        const float4 w4 = *reinterpret_cast<const float4*>(&wc[d * 20 + 16]);
        acc[0] = fmaf(xx, w0.x, acc[0]);   acc[1] = fmaf(xx, w0.y, acc[1]);
        acc[2] = fmaf(xx, w0.z, acc[2]);   acc[3] = fmaf(xx, w0.w, acc[3]);
        acc[4] = fmaf(xx, w1.x, acc[4]);   acc[5] = fmaf(xx, w1.y, acc[5]);
        acc[6] = fmaf(xx, w1.z, acc[6]);   acc[7] = fmaf(xx, w1.w, acc[7]);
        acc[8] = fmaf(xx, w2.x, acc[8]);   acc[9] = fmaf(xx, w2.y, acc[9]);
        acc[10] = fmaf(xx, w2.z, acc[10]); acc[11] = fmaf(xx, w2.w, acc[11]);
        acc[12] = fmaf(xx, w3.x, acc[12]); acc[13] = fmaf(xx, w3.y, acc[13]);
        acc[14] = fmaf(xx, w3.z, acc[14]); acc[15] = fmaf(xx, w3.w, acc[15]);
        acc[16] = fmaf(xx, w4.x, acc[16]); acc[17] = fmaf(xx, w4.y, acc[17]);
        acc[18] = fmaf(xx, w4.z, acc[18]); acc[19] = fmaf(xx, w4.w, acc[19]);
      }
    }
  }

  // Tail d = 2000 (slice 3 only): per-lane X read + wave-uniform W (tiny).
  if (slice == NSLICE - 1) {
    const int r = valid ? row0 : NN - 1;
    const float xx = X[(size_t)r * DD + 2000];
#pragma unroll
    for (int c = 0; c < CC; ++c)
      acc[c] = fmaf(xx, Wt[2000 * CC + c], acc[c]);
  }

  // Coalesced partial stores: part[slice][c][row].
  if (valid) {
    float* pb = part + (size_t)slice * CC * NN + row0;
#pragma unroll
    for (int c = 0; c < CC; ++c) pb[(size_t)c * NN] = acc[c];
  }
}

// Per-row loss from partials; block-reduce; atomicAdd into out (out holds the
// reg term already, written by reg_kernel earlier on the stream).
__global__ __launch_bounds__(256) void loss_epilogue(
    const float* __restrict__ part,
    const int* __restrict__ Y,
    float* __restrict__ out) {
  const int i = blockIdx.x * 256 + threadIdx.x;
  const bool valid = i < NN;
  const int row = valid ? i : NN - 1;

  float sc[CC];
#pragma unroll
  for (int c = 0; c < CC; ++c) {
    float s = 0.f;
#pragma unroll
    for (int sl = 0; sl < NSLICE; ++sl)
      s += part[((size_t)(sl * CC + c)) * NN + row];   // coalesced
    sc[c] = s;
  }

  float mx = -3.402823466e38f;
#pragma unroll
  for (int c = 0; c < CC; ++c) mx = fmaxf(mx, -sc[c]);
  float se = 0.f;
#pragma unroll
  for (int c = 0; c < CC; ++c) se += __expf(-sc[c] - mx);
  const int y = valid ? Y[row] : 0;
  float picked = 0.f;
#pragma unroll
  for (int c = 0; c < CC; ++c) picked = (c == y) ? sc[c] : picked;
  float li = valid ? (picked + mx + __logf(se)) : 0.f;

#pragma unroll
  for (int off = 32; off > 0; off >>= 1) li += __shfl_xor(li, off, 64);
  __shared__ float red[4];
  if ((threadIdx.x & 63) == 0) red[threadIdx.x >> 6] = li;
  __syncthreads();
  if (threadIdx.x == 0)
    atomicAdd(out, (red[0] + red[1] + red[2] + red[3]) * (1.0f / NN));
}

// Runs FIRST: out[0] = REG * ||init_weights||_F (plain store, clears poison).
__global__ void reg_kernel(const float* __restrict__ IW, float* __restrict__ out) {
  __shared__ float red[256];
  float s = 0.f;
  for (int i = threadIdx.x; i < CC * DD; i += 256) {
    float v = IW[i];
    s += v * v;
  }
  red[threadIdx.x] = s;
  __syncthreads();
  for (int w = 128; w > 0; w >>= 1) {
    if (threadIdx.x < w) red[threadIdx.x] += red[threadIdx.x + w];
    __syncthreads();
  }
  if (threadIdx.x == 0) out[0] = REGC * sqrtf(red[0]);
}

__global__ void transpose_w(const float* __restrict__ W, float* __restrict__ Wt) {
  int i = blockIdx.x * 256 + threadIdx.x;
  if (i < CC * DD) {
    int c = i / DD;
    int d = i - c * DD;
    Wt[d * CC + c] = W[i];
  }
}

extern "C" void kernel_launch(void* const* d_in, const int* in_sizes, int n_in,
                              void* d_out, int out_size, void* d_ws, size_t ws_size,
                              hipStream_t stream) {
  const float* W  = (const float*)d_in[0];   // weights [C, D]
  const float* X  = (const float*)d_in[1];   // X [N, D]
  const int*   Y  = (const int*)d_in[2];     // Y [N]
  const float* IW = (const float*)d_in[3];   // init_weights [C, D]
  float* out = (float*)d_out;

  float* part = (float*)d_ws;                          // 32 MB partials
  float* Wt = (float*)((char*)d_ws + PART_BYTES);      // 160 KB transposed W

  // 1) constant reg term (overwrites poisoned d_out)
  reg_kernel<<<1, 256, 0, stream>>>(IW, out);
  // 2) transpose weights -> Wt[d][c]
  transpose_w<<<(CC * DD + 255) / 256, 256, 0, stream>>>(W, Wt);
  // 3) main streaming kernel: 1563 row-groups x 4 D-slices, 64-thread waves
  dim3 grid(NRG, NSLICE);
  loss_partial<<<grid, 64, 0, stream>>>(X, Wt, part);
  // 4) epilogue: combine partials, per-row loss, mean, += into out
  loss_epilogue<<<(NN + 255) / 256, 256, 0, stream>>>(part, Y, out);
}